// Round 13
// baseline (28.145 us; speedup 1.0000x reference)
//
#include <hip/hip_runtime.h>

// MTGP covariance, round 13: persistent 2-tile blocks, cross-tile pipelining.
// cov[i,j] = sum_z W[ti,z]W[tj,z]*th[z,0]*exp(-0.5*th[z,1]*||Xi-Xj||^2) + 0.002*I
// M=4096, D=64, Z=4, fp32 in/out. Single fused kernel, grid=1024 (4 blocks/CU,
// 33KB LDS -> fully resident/persistent). Block b: items {2b, 2b+1} (+2048+b
// for b<32) of the 2080-item upper-tri 64x64 tile list.
// Per tile: K-loop(R7: 16 ds_read_b128 + 24 mfma 16x16x32 bf16 hh+hl+lh) ->
// barrier -> issue NEXT tile's staging loads -> epilogue+stores(current) ->
// convert/write next panels+norms (banked nrm[2]) -> barrier. Store drain of
// tile t overlaps K-loop of t+1. A-panel reused when u unchanged.
// Exact-once coverage (direct upper + mirror strictly-lower), deterministic.

#define M_PTS 4096
#define DIM 64
#define JITTER_F 0.002f
#define NEG_HALF_LOG2E (-0.72134752044448170f)  // -0.5*log2(e)

typedef __attribute__((ext_vector_type(8))) short short8v;   // 8 bf16
typedef __attribute__((ext_vector_type(4))) float f32x4;

union FragU { short8v v; uint4 u; };

__device__ __forceinline__ float fast_exp2(float x) {
#if defined(__has_builtin)
#if __has_builtin(__builtin_amdgcn_exp2f)
  return __builtin_amdgcn_exp2f(x);
#else
  return exp2f(x);
#endif
#else
  return exp2f(x);
#endif
}

__device__ __forceinline__ unsigned bfr(float x) {  // fp32 -> bf16 (rne), as u16
  unsigned u = __float_as_uint(x);
  return (u + 0x7FFFu + ((u >> 16) & 1u)) >> 16;
}
__device__ __forceinline__ float bff(unsigned h) {  // bf16 bits -> fp32
  return __uint_as_float(h << 16);
}

// convert 8 staged float4 (one row-half) -> hi/lo panels (k-permuted, swizzled)
// + row-half norm partial (fixed ascending order -> deterministic)
__device__ __forceinline__ void cvt_write(const float4* xv, unsigned short* Ph,
                                          unsigned short* Pl, int srow, int half,
                                          float& sout) {
  float s = 0.0f;
#pragma unroll
  for (int kgs = 0; kgs < 4; ++kgs) {
    const float4 v0 = xv[kgs];
    const float4 v1 = xv[kgs + 4];
    s = fmaf(v0.x, v0.x, s); s = fmaf(v0.y, v0.y, s);
    s = fmaf(v0.z, v0.z, s); s = fmaf(v0.w, v0.w, s);
    s = fmaf(v1.x, v1.x, s); s = fmaf(v1.y, v1.y, s);
    s = fmaf(v1.z, v1.z, s); s = fmaf(v1.w, v1.w, s);
    const unsigned h0 = bfr(v0.x), h1 = bfr(v0.y), h2 = bfr(v0.z), h3 = bfr(v0.w);
    const unsigned h4 = bfr(v1.x), h5 = bfr(v1.y), h6 = bfr(v1.z), h7 = bfr(v1.w);
    const uint4 hv = make_uint4(h0 | (h1 << 16), h2 | (h3 << 16),
                                h4 | (h5 << 16), h6 | (h7 << 16));
    const uint4 lv = make_uint4(
        bfr(v0.x - bff(h0)) | (bfr(v0.y - bff(h1)) << 16),
        bfr(v0.z - bff(h2)) | (bfr(v0.w - bff(h3)) << 16),
        bfr(v1.x - bff(h4)) | (bfr(v1.y - bff(h5)) << 16),
        bfr(v1.z - bff(h6)) | (bfr(v1.w - bff(h7)) << 16));
    const int f = (half << 2) + kgs;
    const int lofs = srow * 64 + ((f ^ (srow & 7)) << 3);
    *(uint4*)&Ph[lofs] = hv;
    *(uint4*)&Pl[lofs] = lv;
  }
  sout = s;
}

__device__ __forceinline__ void decode_item(int item, int& uu, int& vv) {
  int u = (int)(64.5f - sqrtf(4160.25f - 2.0f * (float)item));
  if (u < 0) u = 0;
  if (u > 63) u = 63;
  while (u > 0 && u * (129 - u) / 2 > item) --u;
  while (u < 63 && (u + 1) * (128 - u) / 2 <= item) ++u;
  uu = u;
  vv = u + (item - u * (129 - u) / 2);
}

__global__ __launch_bounds__(256, 4) void mtgp_persist(
    const float* __restrict__ X,      // [4096,64]
    const float* __restrict__ W,      // [4,4]
    const float* __restrict__ theta,  // [4,2]
    float* __restrict__ out) {        // [4096,4096]
  __shared__ __align__(16) unsigned short Ahi[4096], Alo[4096];  // 8KB each
  __shared__ __align__(16) unsigned short Bhi[4096], Blo[4096];  // 8KB each
  __shared__ float nrm[2][128];                                  // 1KB banked

  const int b = blockIdx.x;
  const int nt = (b < 32) ? 3 : 2;

  const int tid = threadIdx.x;
  const int half = tid & 1;
  const int srow = (tid & 127) >> 1;
  const bool isB = (tid >= 128);
  const int wid = tid >> 6, lane = tid & 63;
  const int wr = (wid >> 1) << 5;          // wave row offset (0/32)
  const int wc = (wid & 1) << 5;           // wave col offset (0/32)
  const int r16 = lane & 15, kg = lane >> 4, kg4 = kg << 2;

  int u, v;
  decode_item(2 * b, u, v);
  int curU = u;

  // ---- initial stage: tile 0 (A rows: tid<128, B rows: tid>=128) ----
  {
    float4 xv[8];
    const int grow = ((isB ? v : u) << 6) + srow;
    const float4* xr = (const float4*)(X + (size_t)grow * DIM + half * 32);
#pragma unroll
    for (int i = 0; i < 8; ++i) xv[i] = xr[i];
    float s;
    cvt_write(xv, isB ? Bhi : Ahi, isB ? Blo : Alo, srow, half, s);
    s += __shfl_xor(s, 1);
    if (half == 0) nrm[0][(isB ? 64 : 0) + srow] = s;
  }
  __syncthreads();

#pragma unroll 1
  for (int t = 0; t < nt; ++t) {
    const int bank = t & 1;
    const int grow0 = u << 6, gj0 = v << 6;

    // ---- K-loop (R7 verified) ----
    f32x4 acc[2][2];
#pragma unroll
    for (int p = 0; p < 2; ++p) { acc[p][0] = (f32x4)0.0f; acc[p][1] = (f32x4)0.0f; }
#define FRAG_LD(dst, PANEL, rr) { \
    dst.u = *(const uint4*)&PANEL[(rr) * 64 + ((f0 ^ ((rr) & 7)) << 3)]; }
#pragma unroll
    for (int k0 = 0; k0 < 2; ++k0) {
      const int f0 = (k0 << 2) + kg;
      FragU ah[2], al[2], bh[2], bl[2];
#pragma unroll
      for (int p = 0; p < 2; ++p) {
        const int ra = wr + p * 16 + r16;
        const int rb = wc + p * 16 + r16;
        FRAG_LD(ah[p], Ahi, ra)
        FRAG_LD(al[p], Alo, ra)
        FRAG_LD(bh[p], Bhi, rb)
        FRAG_LD(bl[p], Blo, rb)
      }
#pragma unroll
      for (int p = 0; p < 2; ++p)
#pragma unroll
        for (int q = 0; q < 2; ++q) {
          acc[p][q] = __builtin_amdgcn_mfma_f32_16x16x32_bf16(ah[p].v, bh[q].v, acc[p][q], 0, 0, 0);
          acc[p][q] = __builtin_amdgcn_mfma_f32_16x16x32_bf16(ah[p].v, bl[q].v, acc[p][q], 0, 0, 0);
          acc[p][q] = __builtin_amdgcn_mfma_f32_16x16x32_bf16(al[p].v, bh[q].v, acc[p][q], 0, 0, 0);
        }
    }
#undef FRAG_LD
    __syncthreads();  // panels + nrm[bank^1] dead for writes after this

    // ---- issue next tile's staging loads (latency hides under epilogue) ----
    const bool hav = (t + 1 < nt);
    int u2 = u, v2 = v;
    bool iload = false;
    float4 xv[8];
    if (hav) {
      decode_item((t + 1 == 1) ? (2 * b + 1) : (2048 + b), u2, v2);
      const bool achg = (u2 != curU);
      iload = isB || achg;
      if (iload) {
        const int grow = ((isB ? v2 : u2) << 6) + srow;
        const float4* xr = (const float4*)(X + (size_t)grow * DIM + half * 32);
#pragma unroll
        for (int i = 0; i < 8; ++i) xv[i] = xr[i];
      }
      if (!achg && tid < 64) nrm[bank ^ 1][tid] = nrm[bank][tid];  // A norms carry
    }

    // ---- epilogue (reads nrm[bank]) ----
    const int ti = u >> 4, tj = v >> 4;
    float czv[4], ezv[4];
#pragma unroll
    for (int z = 0; z < 4; ++z) {
      czv[z] = W[ti * 4 + z] * W[tj * 4 + z] * theta[2 * z];
      ezv[z] = NEG_HALF_LOG2E * theta[2 * z + 1];
    }
    f32x4 sqr[2];
#pragma unroll
    for (int p = 0; p < 2; ++p) sqr[p] = *(const f32x4*)&nrm[bank][wr + p * 16 + kg4];
    float sqc[2];
#pragma unroll
    for (int q = 0; q < 2; ++q) sqc[q] = nrm[bank][64 + wc + q * 16 + r16];

#pragma unroll
    for (int p = 0; p < 2; ++p)
#pragma unroll
      for (int q = 0; q < 2; ++q)
#pragma unroll
        for (int rr = 0; rr < 4; ++rr) {
          const float d = acc[p][q][rr];
          const float sd = fmaxf(fmaf(-2.0f, d, sqr[p][rr] + sqc[q]), 0.0f);
          float val = czv[0] * fast_exp2(ezv[0] * sd);
          val = fmaf(czv[1], fast_exp2(ezv[1] * sd), val);
          val = fmaf(czv[2], fast_exp2(ezv[2] * sd), val);
          val = fmaf(czv[3], fast_exp2(ezv[3] * sd), val);
          if (u == v && wr + p * 16 + kg4 + rr == wc + q * 16 + r16) val += JITTER_F;
          acc[p][q][rr] = val;
        }

    // ---- stores (R7 verified pattern; drain overlaps next K-loop) ----
#pragma unroll
    for (int p = 0; p < 2; ++p)
#pragma unroll
      for (int rr = 0; rr < 4; ++rr) {
        float* rp = out + (size_t)(grow0 + wr + p * 16 + kg4 + rr) * M_PTS + gj0 + wc + r16;
        rp[0] = acc[p][0][rr];
        rp[16] = acc[p][1][rr];
      }
    if (u != v) {
#pragma unroll
      for (int q = 0; q < 2; ++q)
#pragma unroll
        for (int p = 0; p < 2; ++p) {
          f32x4* tp = (f32x4*)(out + (size_t)(gj0 + wc + q * 16 + r16) * M_PTS + grow0 + wr + p * 16 + kg4);
          *tp = acc[p][q];
        }
    }

    // ---- finish restage: convert + write panels/norms for tile t+1 ----
    if (hav) {
      if (iload) {
        float s;
        cvt_write(xv, isB ? Bhi : Ahi, isB ? Blo : Alo, srow, half, s);
        s += __shfl_xor(s, 1);
        if (half == 0) nrm[bank ^ 1][(isB ? 64 : 0) + srow] = s;
      }
      curU = u2;
      u = u2;
      v = v2;
    }
    __syncthreads();
  }
}

extern "C" void kernel_launch(void* const* d_in, const int* in_sizes, int n_in,
                              void* d_out, int out_size, void* d_ws, size_t ws_size,
                              hipStream_t stream) {
  const float* x     = (const float*)d_in[0];   // (4,1024,64)
  const float* W     = (const float*)d_in[1];   // (4,4)
  const float* theta = (const float*)d_in[2];   // (4,2)
  float* out = (float*)d_out;                   // (4096,4096)

  mtgp_persist<<<dim3(1024), dim3(256), 0, stream>>>(x, W, theta, out);
}